// Round 3
// baseline (454.721 us; speedup 1.0000x reference)
//
#include <hip/hip_runtime.h>
#include <math.h>

#define BPIX 64      // pixels per block
#define HW   76800   // H*W
#define W_   320
#define H_   240
#define ENC_W 160
#define ENC_H 120
#define CENC 64
#define CSEG 21
#define NCH  85      // CENC + CSEG
#define ROW  90      // 2 + 85 + 3
#define PIXF 630     // 7 * 90
#define PIXF2 315    // PIXF / 2

// ---------------------------------------------------------------------------
// Per-batch constants: K_inv (16), c2f translation -fmin/VOXEL (3), pad_off (3)
// ---------------------------------------------------------------------------
__global__ void setup_consts_kernel(const float* __restrict__ intr,
                                    float* __restrict__ C) {
  int b = threadIdx.x;
  if (b >= 2) return;
  float A[4][4], inv[4][4];
  for (int r = 0; r < 4; ++r)
    for (int c = 0; c < 4; ++c) {
      A[r][c] = intr[b * 16 + r * 4 + c];
      inv[r][c] = (r == c) ? 1.f : 0.f;
    }
  // Gauss-Jordan with partial pivoting (matches LU-based inv well within tol)
  for (int k = 0; k < 4; ++k) {
    int piv = k; float best = fabsf(A[k][k]);
    for (int r = k + 1; r < 4; ++r) {
      float v = fabsf(A[r][k]);
      if (v > best) { best = v; piv = r; }
    }
    if (piv != k) {
      for (int c = 0; c < 4; ++c) {
        float t = A[k][c]; A[k][c] = A[piv][c]; A[piv][c] = t;
        t = inv[k][c]; inv[k][c] = inv[piv][c]; inv[piv][c] = t;
      }
    }
    float ip = 1.f / A[k][k];
    for (int c = 0; c < 4; ++c) { A[k][c] *= ip; inv[k][c] *= ip; }
    for (int r = 0; r < 4; ++r) if (r != k) {
      float f = A[r][k];
      for (int c = 0; c < 4; ++c) { A[r][c] -= f * A[k][c]; inv[r][c] -= f * inv[k][c]; }
    }
  }
  // frustum corners at DMIN/DMAX
  const float cpx[4][2] = {{0.f, 0.f}, {320.f, 0.f}, {0.f, 240.f}, {320.f, 240.f}};
  float fmn[3] = {1e30f, 1e30f, 1e30f}, fmx[3] = {-1e30f, -1e30f, -1e30f};
  for (int zi = 0; zi < 2; ++zi) {
    float z = zi ? 6.0f : 0.4f;
    for (int i = 0; i < 4; ++i) {
      float px = cpx[i][0] * z, py = cpx[i][1] * z;
      for (int ax = 0; ax < 3; ++ax) {
        float v = inv[ax][0] * px + inv[ax][1] * py + inv[ax][2] * z + inv[ax][3];
        fmn[ax] = fminf(fmn[ax], v);
        fmx[ax] = fmaxf(fmx[ax], v);
      }
    }
  }
  float* Cb = C + b * 32;
  for (int r = 0; r < 4; ++r)
    for (int c = 0; c < 4; ++c) Cb[r * 4 + c] = inv[r][c];
  for (int ax = 0; ax < 3; ++ax) {
    Cb[16 + ax] = -fmn[ax] / 0.03f;                              // c2f translation
    Cb[19 + ax] = (256.0f - (fmx[ax] - fmn[ax]) / 0.03f) * 0.5f; // pad_off
  }
}

// ---------------------------------------------------------------------------
// Main kernel: 64 pixels per block (one image row segment), 256 threads.
// Phase 0: per-pixel scalars + bilinear tap offsets/weights (threads 0..63)
// Phase 1: samp[p][ch] = bilinear(enc|seg) * m   (lanes=pixels -> coalesced)
// Phase 2: stream 64*630 floats out as float2   (perfectly coalesced)
// ---------------------------------------------------------------------------
__global__ __launch_bounds__(256) void sparse_proj_kernel(
    const float* __restrict__ depth, const float* __restrict__ enc,
    const float* __restrict__ seg, const float* __restrict__ C,
    float* __restrict__ out) {
  __shared__ float sampM[BPIX * NCH];
  __shared__ float mArr[BPIX], fracArr[BPIX], fc0[BPIX], fc1[BPIX], fc2[BPIX];
  __shared__ int   eo0[BPIX], eo1[BPIX], eo2[BPIX], eo3[BPIX];
  __shared__ float ew0[BPIX], ew1[BPIX], ew2[BPIX], ew3[BPIX];
  __shared__ int   so0[BPIX], so1[BPIX], so2[BPIX], so3[BPIX];
  __shared__ float sw0[BPIX], sw1[BPIX], sw2[BPIX], sw3[BPIX];

  const int tid = threadIdx.x;
  const int bx = blockIdx.x;
  const int b  = blockIdx.y;
  const float* Cb = C + b * 32;

  if (tid < BPIX) {
    const int p = tid;
    const int gpix = bx * BPIX + p;
    const int x = gpix % W_;
    const int y = gpix / W_;
    const float d = depth[(size_t)b * HW + gpix];
    const bool val = (d >= 0.4f) && (d <= 6.0f);
    const float m = val ? 1.f : 0.f;
    const float z = val ? d : 0.f;
    const float nx = (float)x / 320.f;
    const float ny = (float)y / 240.f;
    const float xv = nx * 320.f * z;   // replicate reference rounding path
    const float yv = ny * 240.f * z;
    const float q0 = Cb[0] * xv + Cb[1] * yv + Cb[2] * z + Cb[3];
    const float q1 = Cb[4] * xv + Cb[5] * yv + Cb[6] * z + Cb[7];
    const float q2 = Cb[8] * xv + Cb[9] * yv + Cb[10] * z + Cb[11];
    const float q3 = Cb[12] * xv + Cb[13] * yv + Cb[14] * z + Cb[15];
    const float INV_V = (float)(1.0 / 0.03);
    const float gcx = q0 * INV_V + Cb[16] * q3;
    const float gcy = q1 * INV_V + Cb[17] * q3;
    const float gcz = q2 * INV_V + Cb[18] * q3;
    mArr[p] = m;
    fracArr[p] = gcz - truncf(gcz);
    fc0[p] = (gcx + Cb[19]) * m;
    fc1[p] = (gcy + Cb[20]) * m;
    fc2[p] = (gcz + Cb[21]) * m;
    {  // encoder taps: grid (nx,ny) on 160x120
      const float ix = nx * 160.f - 0.5f;
      const float iy = ny * 120.f - 0.5f;
      const float x0f = floorf(ix), y0f = floorf(iy);
      const float wx = ix - x0f, wy = iy - y0f;
      const int x0 = (int)x0f, y0 = (int)y0f;
      const int x1 = x0 + 1, y1 = y0 + 1;
      const float vx0 = (x0 >= 0 && x0 < 160) ? 1.f : 0.f;
      const float vx1 = (x1 >= 0 && x1 < 160) ? 1.f : 0.f;
      const float vy0 = (y0 >= 0 && y0 < 120) ? 1.f : 0.f;
      const float vy1 = (y1 >= 0 && y1 < 120) ? 1.f : 0.f;
      const int xc0 = min(max(x0, 0), 159), xc1 = min(max(x1, 0), 159);
      const int yc0 = min(max(y0, 0), 119), yc1 = min(max(y1, 0), 119);
      eo0[p] = yc0 * 160 + xc0; ew0[p] = (1.f - wx) * (1.f - wy) * vx0 * vy0;
      eo1[p] = yc0 * 160 + xc1; ew1[p] = wx * (1.f - wy) * vx1 * vy0;
      eo2[p] = yc1 * 160 + xc0; ew2[p] = (1.f - wx) * wy * vx0 * vy1;
      eo3[p] = yc1 * 160 + xc1; ew3[p] = wx * wy * vx1 * vy1;
    }
    {  // seg taps: grid (nx,ny) on 320x240
      const float ix = nx * 320.f - 0.5f;
      const float iy = ny * 240.f - 0.5f;
      const float x0f = floorf(ix), y0f = floorf(iy);
      const float wx = ix - x0f, wy = iy - y0f;
      const int x0 = (int)x0f, y0 = (int)y0f;
      const int x1 = x0 + 1, y1 = y0 + 1;
      const float vx0 = (x0 >= 0 && x0 < 320) ? 1.f : 0.f;
      const float vx1 = (x1 >= 0 && x1 < 320) ? 1.f : 0.f;
      const float vy0 = (y0 >= 0 && y0 < 240) ? 1.f : 0.f;
      const float vy1 = (y1 >= 0 && y1 < 240) ? 1.f : 0.f;
      const int xc0 = min(max(x0, 0), 319), xc1 = min(max(x1, 0), 319);
      const int yc0 = min(max(y0, 0), 239), yc1 = min(max(y1, 0), 239);
      so0[p] = yc0 * 320 + xc0; sw0[p] = (1.f - wx) * (1.f - wy) * vx0 * vy0;
      so1[p] = yc0 * 320 + xc1; sw1[p] = wx * (1.f - wy) * vx1 * vy0;
      so2[p] = yc1 * 320 + xc0; sw2[p] = (1.f - wx) * wy * vx0 * vy1;
      so3[p] = yc1 * 320 + xc1; sw3[p] = wx * wy * vx1 * vy1;
    }
  }
  __syncthreads();

  // Phase 1: lanes = pixels (coalesced taps), loop over 85 channels
  for (int idx = tid; idx < BPIX * NCH; idx += 256) {
    const int p = idx & (BPIX - 1);
    const int ch = idx >> 6;   // wave-uniform
    float v;
    if (ch < CENC) {
      const float* fb = enc + ((size_t)b * CENC + ch) * (ENC_H * ENC_W);
      v = ew0[p] * fb[eo0[p]] + ew1[p] * fb[eo1[p]] +
          ew2[p] * fb[eo2[p]] + ew3[p] * fb[eo3[p]];
    } else {
      const float* fb = seg + ((size_t)b * CSEG + (ch - CENC)) * (size_t)HW;
      v = sw0[p] * fb[so0[p]] + sw1[p] * fb[so1[p]] +
          sw2[p] * fb[so2[p]] + sw3[p] * fb[so3[p]];
    }
    sampM[p * NCH + ch] = v * mArr[p];
  }
  __syncthreads();

  // Phase 2: stream out. Block chunk = 64*630 floats, contiguous & 16B-aligned.
  float2* out2 = reinterpret_cast<float2*>(out + (size_t)(b * HW + bx * BPIX) * PIXF);
  for (int j = tid; j < BPIX * PIXF2; j += 256) {
    const int p = j / PIXF2;          // magic-mul
    const int t2 = j - p * PIXF2;
    const int fi = t2 * 2;            // 0..628, even
    const int r = fi / ROW;           // magic-mul
    const int c = fi - r * ROW;       // even
    const float m = mArr[p];
    float2 v;
    if (c == 0) {
      const float df = fracArr[p] + (float)(r - 3);
      const float s = (df > 0.f) ? 1.f : ((df < 0.f) ? -1.f : 0.f);
      v.x = s * m;
      v.y = fabsf(df) * m;
    } else if (c < 86) {
      v.x = sampM[p * NCH + (c - 2)];
      v.y = sampM[p * NCH + (c - 1)];
    } else if (c == 86) {
      v.x = sampM[p * NCH + 84];
      v.y = fc0[p];
    } else {  // c == 88
      v.x = fc1[p];
      v.y = fc2[p] + (float)(r - 3) * m;
    }
    out2[j] = v;
  }
}

extern "C" void kernel_launch(void* const* d_in, const int* in_sizes, int n_in,
                              void* d_out, int out_size, void* d_ws, size_t ws_size,
                              hipStream_t stream) {
  const float* depth = (const float*)d_in[0];
  const float* enc   = (const float*)d_in[1];
  const float* seg   = (const float*)d_in[2];
  const float* intr  = (const float*)d_in[3];
  float* out = (float*)d_out;
  float* C   = (float*)d_ws;   // 2 * 32 floats

  setup_consts_kernel<<<1, 64, 0, stream>>>(intr, C);
  dim3 grid(HW / BPIX, 2);
  sparse_proj_kernel<<<grid, 256, 0, stream>>>(depth, enc, seg, C, out);
}